// Round 9
// baseline (250.959 us; speedup 1.0000x reference)
//
#include <hip/hip_runtime.h>
#include <hip/hip_bf16.h>
#include <stdint.h>

using bf16 = __hip_bfloat16;
typedef __attribute__((ext_vector_type(8))) short short8;
typedef __attribute__((ext_vector_type(4))) float floatx4;
typedef __attribute__((ext_vector_type(4))) unsigned int uintx4;

constexpr int BATCH = 2;
constexpr int SEQ   = 2048;
constexpr int NH    = 16;
constexpr int DH    = 64;
constexpr int DM    = 1024;
constexpr int MROWS = BATCH * SEQ;        // 4096
constexpr int OUTN  = MROWS * DM;         // 4194304
constexpr int WN    = DM * DM;            // 1048576

__device__ inline short bfbits(float x) {
    bf16 h = __float2bfloat16(x);
    return __builtin_bit_cast(short, h);
}

// async global->LDS, 16B per lane (m97 pattern)
__device__ inline void async16(bf16* lds, const bf16* g) {
    __builtin_amdgcn_global_load_lds(
        (const __attribute__((address_space(1))) unsigned int*)g,
        (__attribute__((address_space(3))) unsigned int*)lds, 16, 0, 0);
}

// ============ fp32 -> bf16 pre-convert: x|wq|wk|wv into d_out scratch ============
__global__ __launch_bounds__(256)
void cvt_inputs(const float* __restrict__ x,  const float* __restrict__ wq,
                const float* __restrict__ wk, const float* __restrict__ wv,
                bf16* __restrict__ dst)
{
    const size_t i = ((size_t)blockIdx.x * 256 + threadIdx.x) * 8;
    const float* src; size_t off;
    if (i < (size_t)OUTN)               { src = x;  off = i; }
    else if (i < (size_t)OUTN + WN)     { src = wq; off = i - OUTN; }
    else if (i < (size_t)OUTN + 2 * WN) { src = wk; off = i - OUTN - WN; }
    else                                { src = wv; off = i - OUTN - 2 * (size_t)WN; }
    float4 f0 = *(const float4*)(src + off);
    float4 f1 = *(const float4*)(src + off + 4);
    short8 o;
    o[0] = bfbits(f0.x); o[1] = bfbits(f0.y); o[2] = bfbits(f0.z); o[3] = bfbits(f0.w);
    o[4] = bfbits(f1.x); o[5] = bfbits(f1.y); o[6] = bfbits(f1.z); o[7] = bfbits(f1.w);
    *(short8*)(dst + i) = o;
}

__global__ __launch_bounds__(256)
void cvt_wo(const float* __restrict__ wo, bf16* __restrict__ dst)
{
    const size_t i = ((size_t)blockIdx.x * 256 + threadIdx.x) * 8;
    float4 f0 = *(const float4*)(wo + i);
    float4 f1 = *(const float4*)(wo + i + 4);
    short8 o;
    o[0] = bfbits(f0.x); o[1] = bfbits(f0.y); o[2] = bfbits(f0.z); o[3] = bfbits(f0.w);
    o[4] = bfbits(f1.x); o[5] = bfbits(f1.y); o[6] = bfbits(f1.z); o[7] = bfbits(f1.w);
    *(short8*)(dst + i) = o;
}

// ============ bf16 MFMA GEMM with global_load_lds staging (m97 structure) ============
// MODE 0: A = xb; z selects (wq->q PRESCALED 0.125)(wk->k)(wv->vT)
// MODE 1: A gathered from [B,H,S,DH]; output fp32 row-major [B,S,DM]
template<int MODE>
__global__ __launch_bounds__(256)
void gemm_mfma(const bf16* __restrict__ A,
               const bf16* __restrict__ W0, const bf16* __restrict__ W1,
               const bf16* __restrict__ W2,
               bf16* __restrict__ C0, bf16* __restrict__ C1, bf16* __restrict__ C2,
               float* __restrict__ F)
{
    __shared__ __align__(16) bf16 As[128 * 32];
    __shared__ __align__(16) bf16 Ws[128 * 32];

    const int t    = threadIdx.x;
    const int wave = t >> 6;
    const int lane = t & 63;
    const int quad = lane >> 4;
    const int l16  = lane & 15;
    const int m0 = blockIdx.y * 128;
    const int n0 = blockIdx.x * 128;
    const int wr = (wave >> 1) * 64;
    const int wc = (wave & 1) * 64;

    const int z = (MODE == 0) ? blockIdx.z : 0;
    const bf16* W = (z == 0) ? W0 : ((z == 1) ? W1 : W2);

    const int c    = t;
    bf16* lA0 = As + c * 8;          bf16* lA1 = As + c * 8 + 2048;
    bf16* lW0 = Ws + c * 8;          bf16* lW1 = Ws + c * 8 + 2048;
    const int ar0 = m0 + (c >> 2),  ar1 = m0 + 64 + (c >> 2);
    const int nr0 = n0 + (c >> 2),  nr1 = n0 + 64 + (c >> 2);
    const int kc  = (c & 3) * 8;

    floatx4 acc[4][4] = {};

    for (int k0 = 0; k0 < DM; k0 += 32) {
        const bf16 *gA0, *gA1;
        if (MODE == 0) {
            gA0 = A + (size_t)ar0 * DM + k0 + kc;
            gA1 = A + (size_t)ar1 * DM + k0 + kc;
        } else {
            const int k = k0 + kc, h = k >> 6, d = k & (DH - 1);
            gA0 = A + (((size_t)((ar0 >> 11) * NH + h)) * SEQ + (ar0 & (SEQ - 1))) * DH + d;
            gA1 = A + (((size_t)((ar1 >> 11) * NH + h)) * SEQ + (ar1 & (SEQ - 1))) * DH + d;
        }
        const bf16* gW0 = W + (size_t)nr0 * DM + k0 + kc;
        const bf16* gW1 = W + (size_t)nr1 * DM + k0 + kc;

        __syncthreads();
        async16(lA0, gA0);
        async16(lA1, gA1);
        async16(lW0, gW0);
        async16(lW1, gW1);
        __syncthreads();

        short8 af[4], wf[4];
        #pragma unroll
        for (int i = 0; i < 4; i++)
            af[i] = *(const short8*)(As + (wr + i * 16 + l16) * 32 + quad * 8);
        #pragma unroll
        for (int j = 0; j < 4; j++)
            wf[j] = *(const short8*)(Ws + (wc + j * 16 + l16) * 32 + quad * 8);
        #pragma unroll
        for (int i = 0; i < 4; i++)
            #pragma unroll
            for (int j = 0; j < 4; j++)
                acc[i][j] = __builtin_amdgcn_mfma_f32_16x16x32_bf16(af[i], wf[j], acc[i][j], 0, 0, 0);
    }

    // C/D layout: col = lane&15, row = quad*4 + reg  [m89/m91]
    #pragma unroll
    for (int i = 0; i < 4; i++) {
        #pragma unroll
        for (int j = 0; j < 4; j++) {
            #pragma unroll
            for (int r = 0; r < 4; r++) {
                const int gm = m0 + wr + i * 16 + quad * 4 + r;
                const int gn = n0 + wc + j * 16 + l16;
                if (MODE == 1) {
                    F[(size_t)gm * DM + gn] = acc[i][j][r];
                } else {
                    const int b = gm >> 11, s = gm & (SEQ - 1);
                    const int h = gn >> 6,  d = gn & (DH - 1);
                    float av = acc[i][j][r];
                    if (z == 0) av *= 0.125f;                 // fold 1/sqrt(DH) into q
                    const bf16 val = __float2bfloat16(av);
                    if (z == 2)
                        C2[(((size_t)(b * NH + h)) * DH + d) * SEQ + s] = val;   // V^T
                    else if (z == 0)
                        C0[(((size_t)(b * NH + h)) * SEQ + s) * DH + d] = val;
                    else
                        C1[(((size_t)(b * NH + h)) * SEQ + s) * DH + d] = val;
                }
            }
        }
    }
}

// ============ MFMA causal flash attention, BQ=128, in-place on Q [B,H,S,DH] ============
// grid (SEQ/128, NH, BATCH); wave w owns row-groups q0+16w and q0+64+16w.
// b=1 tiles complemented so each CU's block pair has constant total depth.
__global__ __launch_bounds__(256)
void attn_flash(bf16* __restrict__ Q, const bf16* __restrict__ K,
                const bf16* __restrict__ Vt)
{
    constexpr int LK = 72;   // 64 + 8 pad
    __shared__ __align__(16) bf16 Ks[64 * LK];      // [key][dim]
    __shared__ __align__(16) bf16 Vs[64 * LK];      // [dim][key]
    __shared__ __align__(16) bf16 Ps[4][16 * LK];   // per-wave P round-trip (reused per rg)

    const int t    = threadIdx.x;
    const int wave = t >> 6;
    const int lane = t & 63;
    const int quad = lane >> 4;
    const int l16  = lane & 15;

    const int h  = blockIdx.y;
    const int b  = blockIdx.z;
    int qt = (blockIdx.x + 3 * h) & 15;
    if (b) qt = 15 - qt;                  // complementary pairing across batch
    const int q0 = qt * 128;
    const size_t bh = ((size_t)(b * NH + h)) * SEQ * DH;

    // row-group bases: rg0 = q0 + 16*wave, rg1 = rg0 + 64
    const int rb0 = q0 + wave * 16;

    short8 qf[2][2];
    #pragma unroll
    for (int rg = 0; rg < 2; rg++) {
        const int rr = rb0 + rg * 64;
        qf[rg][0] = *(const short8*)(Q + bh + (size_t)(rr + l16) * DH + quad * 8);
        qf[rg][1] = *(const short8*)(Q + bh + (size_t)(rr + l16) * DH + quad * 8 + 32);
    }

    floatx4 oacc[2][4] = {};
    float mrow[2][4], lrow[2][4];
    #pragma unroll
    for (int rg = 0; rg < 2; rg++)
        #pragma unroll
        for (int r = 0; r < 4; r++) { mrow[rg][r] = -1e30f; lrow[rg][r] = 0.f; }

    const int stage_r = t >> 3;        // 0..31
    const int stage_c = (t & 7) * 8;   // 0..56

    for (int k0 = 0; k0 < q0 + 128; k0 += 64) {
        uintx4 kv0 = *(const uintx4*)(K  + bh + (size_t)(k0 + stage_r) * DH + stage_c);
        uintx4 kv1 = *(const uintx4*)(K  + bh + (size_t)(k0 + 32 + stage_r) * DH + stage_c);
        uintx4 vv0 = *(const uintx4*)(Vt + bh + (size_t)stage_r * SEQ + k0 + stage_c);
        uintx4 vv1 = *(const uintx4*)(Vt + bh + (size_t)(stage_r + 32) * SEQ + k0 + stage_c);
        __syncthreads();
        *(uintx4*)(Ks + stage_r * LK + stage_c)        = kv0;
        *(uintx4*)(Ks + (32 + stage_r) * LK + stage_c) = kv1;
        *(uintx4*)(Vs + stage_r * LK + stage_c)        = vv0;
        *(uintx4*)(Vs + (32 + stage_r) * LK + stage_c) = vv1;
        __syncthreads();

        #pragma unroll
        for (int rg = 0; rg < 2; rg++) {
            const int base = rb0 + rg * 64;           // first q-row of this group
            if (k0 > base + 15) continue;             // fully masked for this group

            // ---- scores S[16 x 64] = (0.125*Q) K^T ----
            floatx4 sc[4];
            #pragma unroll
            for (int j = 0; j < 4; j++) {
                short8 kf0 = *(const short8*)(Ks + (j * 16 + l16) * LK + quad * 8);
                short8 kf1 = *(const short8*)(Ks + (j * 16 + l16) * LK + quad * 8 + 32);
                floatx4 cc = {};
                cc = __builtin_amdgcn_mfma_f32_16x16x32_bf16(qf[rg][0], kf0, cc, 0, 0, 0);
                cc = __builtin_amdgcn_mfma_f32_16x16x32_bf16(qf[rg][1], kf1, cc, 0, 0, 0);
                sc[j] = cc;
            }
            // ---- causal mask only on the diagonal chunk ----
            if (k0 + 63 > base) {
                #pragma unroll
                for (int j = 0; j < 4; j++) {
                    const int kg = k0 + j * 16 + l16;
                    #pragma unroll
                    for (int r = 0; r < 4; r++) {
                        const int qg = base + quad * 4 + r;
                        sc[j][r] = (kg <= qg) ? sc[j][r] : -1e30f;
                    }
                }
            }
            // ---- online softmax (16-lane butterfly within quad) ----
            #pragma unroll
            for (int r = 0; r < 4; r++) {
                float mx = fmaxf(fmaxf(sc[0][r], sc[1][r]), fmaxf(sc[2][r], sc[3][r]));
                #pragma unroll
                for (int d = 1; d < 16; d <<= 1) mx = fmaxf(mx, __shfl_xor(mx, d, 64));
                const float mnew  = fmaxf(mrow[rg][r], mx);
                const float alpha = __expf(mrow[rg][r] - mnew);
                float rs = 0.f;
                #pragma unroll
                for (int j = 0; j < 4; j++) {
                    const float p = __expf(sc[j][r] - mnew);
                    sc[j][r] = p;
                    rs += p;
                }
                #pragma unroll
                for (int d = 1; d < 16; d <<= 1) rs += __shfl_xor(rs, d, 64);
                lrow[rg][r] = lrow[rg][r] * alpha + rs;
                mrow[rg][r] = mnew;
                #pragma unroll
                for (int td = 0; td < 4; td++) oacc[rg][td][r] *= alpha;
            }
            // ---- P: C-layout -> A-layout via per-wave LDS (m120 pattern) ----
            bf16* P = &Ps[wave][0];
            #pragma unroll
            for (int j = 0; j < 4; j++)
                #pragma unroll
                for (int r = 0; r < 4; r++)
                    P[(quad * 4 + r) * LK + j * 16 + l16] = __float2bfloat16(sc[j][r]);
            // ---- PV: O += P[16x64] * V[64x64] ----
            #pragma unroll
            for (int ks = 0; ks < 2; ks++) {
                short8 pa = *(const short8*)(P + l16 * LK + ks * 32 + quad * 8);
                #pragma unroll
                for (int td = 0; td < 4; td++) {
                    short8 vf = *(const short8*)(Vs + (td * 16 + l16) * LK + ks * 32 + quad * 8);
                    oacc[rg][td] = __builtin_amdgcn_mfma_f32_16x16x32_bf16(pa, vf, oacc[rg][td], 0, 0, 0);
                }
            }
        }
    }

    #pragma unroll
    for (int rg = 0; rg < 2; rg++)
        #pragma unroll
        for (int td = 0; td < 4; td++)
            #pragma unroll
            for (int r = 0; r < 4; r++) {
                const int qg = rb0 + rg * 64 + quad * 4 + r;
                Q[bh + (size_t)qg * DH + td * 16 + l16] =
                    __float2bfloat16(oacc[rg][td][r] / lrow[rg][r]);
            }
}

extern "C" void kernel_launch(void* const* d_in, const int* in_sizes, int n_in,
                              void* d_out, int out_size, void* d_ws, size_t ws_size,
                              hipStream_t stream)
{
    const float* x  = (const float*)d_in[0];
    const float* wq = (const float*)d_in[1];
    const float* wk = (const float*)d_in[2];
    const float* wv = (const float*)d_in[3];
    const float* wo = (const float*)d_in[4];
    float* out = (float*)d_out;

    // ws (>=24 MB): q | k | vT  bf16
    bf16* qb = (bf16*)d_ws;
    bf16* kb = qb + (size_t)OUTN;
    bf16* vb = kb + (size_t)OUTN;

    // d_out doubles as bf16 scratch until the final GEMM overwrites it
    bf16* xb  = (bf16*)d_out;
    bf16* wqb = xb + (size_t)OUTN;
    bf16* wkb = wqb + WN;
    bf16* wvb = wkb + WN;

    cvt_inputs<<<(OUTN + 3 * WN) / (8 * 256), 256, 0, stream>>>(x, wq, wk, wv, xb);
    gemm_mfma<0><<<dim3(DM / 128, MROWS / 128, 3), dim3(256), 0, stream>>>(
        xb, wqb, wkb, wvb, qb, kb, vb, nullptr);
    attn_flash<<<dim3(SEQ / 128, NH, BATCH), dim3(256), 0, stream>>>(qb, kb, vb);
    bf16* wob = kb;    // kb dead after attention
    cvt_wo<<<WN / (8 * 256), 256, 0, stream>>>(wo, wob);
    gemm_mfma<1><<<dim3(DM / 128, MROWS / 128, 1), dim3(256), 0, stream>>>(
        qb, wob, nullptr, nullptr, nullptr, nullptr, nullptr, out);
}

// Round 10
// 212.079 us; speedup vs baseline: 1.1833x; 1.1833x over previous
//
#include <hip/hip_runtime.h>
#include <hip/hip_bf16.h>
#include <stdint.h>

using bf16 = __hip_bfloat16;
typedef __attribute__((ext_vector_type(8))) short short8;
typedef __attribute__((ext_vector_type(4))) float floatx4;
typedef __attribute__((ext_vector_type(4))) unsigned int uintx4;

constexpr int BATCH = 2;
constexpr int SEQ   = 2048;
constexpr int NH    = 16;
constexpr int DH    = 64;
constexpr int DM    = 1024;
constexpr int MROWS = BATCH * SEQ;        // 4096
constexpr int OUTN  = MROWS * DM;         // 4194304
constexpr int WN    = DM * DM;            // 1048576

__device__ inline short bfbits(float x) {
    bf16 h = __float2bfloat16(x);
    return __builtin_bit_cast(short, h);
}

// async global->LDS, 16B per lane (m97 pattern)
__device__ inline void async16(bf16* lds, const bf16* g) {
    __builtin_amdgcn_global_load_lds(
        (const __attribute__((address_space(1))) unsigned int*)g,
        (__attribute__((address_space(3))) unsigned int*)lds, 16, 0, 0);
}

// ============ fp32 -> bf16 pre-convert: x|wq|wk|wv into d_out scratch ============
__global__ __launch_bounds__(256)
void cvt_inputs(const float* __restrict__ x,  const float* __restrict__ wq,
                const float* __restrict__ wk, const float* __restrict__ wv,
                bf16* __restrict__ dst)
{
    const size_t i = ((size_t)blockIdx.x * 256 + threadIdx.x) * 8;
    const float* src; size_t off;
    if (i < (size_t)OUTN)               { src = x;  off = i; }
    else if (i < (size_t)OUTN + WN)     { src = wq; off = i - OUTN; }
    else if (i < (size_t)OUTN + 2 * WN) { src = wk; off = i - OUTN - WN; }
    else                                { src = wv; off = i - OUTN - 2 * (size_t)WN; }
    float4 f0 = *(const float4*)(src + off);
    float4 f1 = *(const float4*)(src + off + 4);
    short8 o;
    o[0] = bfbits(f0.x); o[1] = bfbits(f0.y); o[2] = bfbits(f0.z); o[3] = bfbits(f0.w);
    o[4] = bfbits(f1.x); o[5] = bfbits(f1.y); o[6] = bfbits(f1.z); o[7] = bfbits(f1.w);
    *(short8*)(dst + i) = o;
}

__global__ __launch_bounds__(256)
void cvt_wo(const float* __restrict__ wo, bf16* __restrict__ dst)
{
    const size_t i = ((size_t)blockIdx.x * 256 + threadIdx.x) * 8;
    float4 f0 = *(const float4*)(wo + i);
    float4 f1 = *(const float4*)(wo + i + 4);
    short8 o;
    o[0] = bfbits(f0.x); o[1] = bfbits(f0.y); o[2] = bfbits(f0.z); o[3] = bfbits(f0.w);
    o[4] = bfbits(f1.x); o[5] = bfbits(f1.y); o[6] = bfbits(f1.z); o[7] = bfbits(f1.w);
    *(short8*)(dst + i) = o;
}

// ============ bf16 MFMA GEMM with global_load_lds staging (m97 structure) ============
// MODE 0: A = xb; z selects (wq->q PRESCALED 0.125)(wk->k)(wv->vT)
// MODE 1: A gathered from [B,H,S,DH]; output fp32 row-major [B,S,DM]
template<int MODE>
__global__ __launch_bounds__(256)
void gemm_mfma(const bf16* __restrict__ A,
               const bf16* __restrict__ W0, const bf16* __restrict__ W1,
               const bf16* __restrict__ W2,
               bf16* __restrict__ C0, bf16* __restrict__ C1, bf16* __restrict__ C2,
               float* __restrict__ F)
{
    __shared__ __align__(16) bf16 As[128 * 32];
    __shared__ __align__(16) bf16 Ws[128 * 32];

    const int t    = threadIdx.x;
    const int wave = t >> 6;
    const int lane = t & 63;
    const int quad = lane >> 4;
    const int l16  = lane & 15;
    const int m0 = blockIdx.y * 128;
    const int n0 = blockIdx.x * 128;
    const int wr = (wave >> 1) * 64;
    const int wc = (wave & 1) * 64;

    const int z = (MODE == 0) ? blockIdx.z : 0;
    const bf16* W = (z == 0) ? W0 : ((z == 1) ? W1 : W2);

    const int c    = t;
    bf16* lA0 = As + c * 8;          bf16* lA1 = As + c * 8 + 2048;
    bf16* lW0 = Ws + c * 8;          bf16* lW1 = Ws + c * 8 + 2048;
    const int ar0 = m0 + (c >> 2),  ar1 = m0 + 64 + (c >> 2);
    const int nr0 = n0 + (c >> 2),  nr1 = n0 + 64 + (c >> 2);
    const int kc  = (c & 3) * 8;

    floatx4 acc[4][4] = {};

    for (int k0 = 0; k0 < DM; k0 += 32) {
        const bf16 *gA0, *gA1;
        if (MODE == 0) {
            gA0 = A + (size_t)ar0 * DM + k0 + kc;
            gA1 = A + (size_t)ar1 * DM + k0 + kc;
        } else {
            const int k = k0 + kc, h = k >> 6, d = k & (DH - 1);
            gA0 = A + (((size_t)((ar0 >> 11) * NH + h)) * SEQ + (ar0 & (SEQ - 1))) * DH + d;
            gA1 = A + (((size_t)((ar1 >> 11) * NH + h)) * SEQ + (ar1 & (SEQ - 1))) * DH + d;
        }
        const bf16* gW0 = W + (size_t)nr0 * DM + k0 + kc;
        const bf16* gW1 = W + (size_t)nr1 * DM + k0 + kc;

        __syncthreads();
        async16(lA0, gA0);
        async16(lA1, gA1);
        async16(lW0, gW0);
        async16(lW1, gW1);
        __syncthreads();

        short8 af[4], wf[4];
        #pragma unroll
        for (int i = 0; i < 4; i++)
            af[i] = *(const short8*)(As + (wr + i * 16 + l16) * 32 + quad * 8);
        #pragma unroll
        for (int j = 0; j < 4; j++)
            wf[j] = *(const short8*)(Ws + (wc + j * 16 + l16) * 32 + quad * 8);
        #pragma unroll
        for (int i = 0; i < 4; i++)
            #pragma unroll
            for (int j = 0; j < 4; j++)
                acc[i][j] = __builtin_amdgcn_mfma_f32_16x16x32_bf16(af[i], wf[j], acc[i][j], 0, 0, 0);
    }

    // C/D layout: col = lane&15, row = quad*4 + reg  [m89/m91]
    #pragma unroll
    for (int i = 0; i < 4; i++) {
        #pragma unroll
        for (int j = 0; j < 4; j++) {
            #pragma unroll
            for (int r = 0; r < 4; r++) {
                const int gm = m0 + wr + i * 16 + quad * 4 + r;
                const int gn = n0 + wc + j * 16 + l16;
                if (MODE == 1) {
                    F[(size_t)gm * DM + gn] = acc[i][j][r];
                } else {
                    const int b = gm >> 11, s = gm & (SEQ - 1);
                    const int h = gn >> 6,  d = gn & (DH - 1);
                    float av = acc[i][j][r];
                    if (z == 0) av *= 0.125f;                 // fold 1/sqrt(DH) into q
                    const bf16 val = __float2bfloat16(av);
                    if (z == 2)
                        C2[(((size_t)(b * NH + h)) * DH + d) * SEQ + s] = val;   // V^T
                    else if (z == 0)
                        C0[(((size_t)(b * NH + h)) * SEQ + s) * DH + d] = val;
                    else
                        C1[(((size_t)(b * NH + h)) * SEQ + s) * DH + d] = val;
                }
            }
        }
    }
}

// ============ MFMA causal flash attention (S^T form), in-place on Q [B,H,S,DH] ============
// grid (32, NH, BATCH), 4 waves, BQ=64; wave w owns q rows [q0+16w, q0+16w+16).
// Computes S^T = K·Q^T so q sits on l16: per-lane scalar m/l, register-shuffle P
// distribution (no LDS round-trip), PV as O^T = V^T·P^T.
__global__ __launch_bounds__(256)
void attn_flash(bf16* __restrict__ Q, const bf16* __restrict__ K,
                const bf16* __restrict__ Vt)
{
    constexpr int LK = 72;   // 64 + 8 pad
    __shared__ __align__(16) bf16 Ks[64 * LK];      // [key][dim]; reused for O transpose
    __shared__ __align__(16) bf16 Vs[64 * LK];      // [dim][key]

    const int t    = threadIdx.x;
    const int wave = t >> 6;
    const int lane = t & 63;
    const int quad = lane >> 4;
    const int l16  = lane & 15;

    const int h  = blockIdx.y;
    const int b  = blockIdx.z;
    const int qt = (blockIdx.x + 5 * h + 16 * b) & 31;   // load-balance swizzle
    const int q0 = qt * 64;
    const size_t bh = ((size_t)(b * NH + h)) * SEQ * DH;

    const int qrow = q0 + wave * 16;
    const int qg   = qrow + l16;          // this lane's q row (S^T col)

    // Q B-frags (bytes identical to A-frag layout): row qrow+l16, dims quad*8..+7
    short8 qf0 = *(const short8*)(Q + bh + (size_t)(qrow + l16) * DH + quad * 8);
    short8 qf1 = *(const short8*)(Q + bh + (size_t)(qrow + l16) * DH + quad * 8 + 32);

    floatx4 oacc[4] = {};                 // O^T tiles: oacc[td][r] = O^T[td*16+quad*4+r][qg]
    float m = -1e30f, l = 0.f;            // per-lane scalars (q = qg)

    const int stage_r = t >> 3;           // 0..31
    const int stage_c = (t & 7) * 8;      // 0..56

    // shuffle-network source lanes (d>>1 = 0 -> sA, 1 -> sB)
    const int sA = (2 * (quad & 1)) * 16 + l16;
    const int sB = sA + 16;
    const bool hiTile = (quad >= 2);      // tile select: 2ks + (quad>>1)

    for (int k0 = 0; k0 < q0 + 64; k0 += 64) {
        uintx4 kv0 = *(const uintx4*)(K  + bh + (size_t)(k0 + stage_r) * DH + stage_c);
        uintx4 kv1 = *(const uintx4*)(K  + bh + (size_t)(k0 + 32 + stage_r) * DH + stage_c);
        uintx4 vv0 = *(const uintx4*)(Vt + bh + (size_t)stage_r * SEQ + k0 + stage_c);
        uintx4 vv1 = *(const uintx4*)(Vt + bh + (size_t)(stage_r + 32) * SEQ + k0 + stage_c);
        __syncthreads();
        *(uintx4*)(Ks + stage_r * LK + stage_c)        = kv0;
        *(uintx4*)(Ks + (32 + stage_r) * LK + stage_c) = kv1;
        *(uintx4*)(Vs + stage_r * LK + stage_c)        = vv0;
        *(uintx4*)(Vs + (32 + stage_r) * LK + stage_c) = vv1;
        __syncthreads();

        if (k0 <= qrow + 15) {
            // ---- S^T[key][q] = K (0.125Q)^T : mfma(A=kf, B=qf) ----
            floatx4 sc[4];
            #pragma unroll
            for (int jj = 0; jj < 4; jj++) {
                short8 kf0 = *(const short8*)(Ks + (jj * 16 + l16) * LK + quad * 8);
                short8 kf1 = *(const short8*)(Ks + (jj * 16 + l16) * LK + quad * 8 + 32);
                floatx4 cc = {};
                cc = __builtin_amdgcn_mfma_f32_16x16x32_bf16(kf0, qf0, cc, 0, 0, 0);
                cc = __builtin_amdgcn_mfma_f32_16x16x32_bf16(kf1, qf1, cc, 0, 0, 0);
                sc[jj] = cc;   // row: key = k0 + jj*16 + quad*4 + r ; col: q = qg
            }
            // ---- causal mask only on the diagonal chunk ----
            if (k0 + 63 > qrow) {
                #pragma unroll
                for (int jj = 0; jj < 4; jj++) {
                    const int kgb = k0 + jj * 16 + quad * 4;
                    #pragma unroll
                    for (int r = 0; r < 4; r++)
                        sc[jj][r] = (kgb + r <= qg) ? sc[jj][r] : -1e30f;
                }
            }
            // ---- online softmax: per-lane scalar state ----
            float mx = sc[0][0];
            #pragma unroll
            for (int jj = 0; jj < 4; jj++)
                #pragma unroll
                for (int r = 0; r < 4; r++) mx = fmaxf(mx, sc[jj][r]);
            mx = fmaxf(mx, __shfl_xor(mx, 16, 64));
            mx = fmaxf(mx, __shfl_xor(mx, 32, 64));
            const float mnew  = fmaxf(m, mx);
            const float alpha = __expf(m - mnew);
            float rs = 0.f;
            #pragma unroll
            for (int jj = 0; jj < 4; jj++)
                #pragma unroll
                for (int r = 0; r < 4; r++) {
                    const float p = __expf(sc[jj][r] - mnew);
                    sc[jj][r] = p;
                    rs += p;
                }
            rs += __shfl_xor(rs, 16, 64);
            rs += __shfl_xor(rs, 32, 64);
            l = l * alpha + rs;
            m = mnew;
            #pragma unroll
            for (int td = 0; td < 4; td++)
                #pragma unroll
                for (int r = 0; r < 4; r++) oacc[td][r] *= alpha;

            // ---- pack P rows into dwords: lo=keys{+0,+1}, hi=keys{+2,+3} ----
            unsigned lo[4], hi[4];
            #pragma unroll
            for (int jj = 0; jj < 4; jj++) {
                lo[jj] = (unsigned)(unsigned short)bfbits(sc[jj][0]) |
                         ((unsigned)(unsigned short)bfbits(sc[jj][1]) << 16);
                hi[jj] = (unsigned)(unsigned short)bfbits(sc[jj][2]) |
                         ((unsigned)(unsigned short)bfbits(sc[jj][3]) << 16);
            }
            // ---- distribute to B-frag of P^T + PV MFMA ----
            #pragma unroll
            for (int ks = 0; ks < 2; ks++) {
                unsigned d0a = __shfl((int)lo[2 * ks],     sA, 64);
                unsigned d0b = __shfl((int)lo[2 * ks + 1], sA, 64);
                unsigned d1a = __shfl((int)hi[2 * ks],     sA, 64);
                unsigned d1b = __shfl((int)hi[2 * ks + 1], sA, 64);
                unsigned d2a = __shfl((int)lo[2 * ks],     sB, 64);
                unsigned d2b = __shfl((int)lo[2 * ks + 1], sB, 64);
                unsigned d3a = __shfl((int)hi[2 * ks],     sB, 64);
                unsigned d3b = __shfl((int)hi[2 * ks + 1], sB, 64);
                uintx4 pw;
                pw[0] = hiTile ? d0b : d0a;
                pw[1] = hiTile ? d1b : d1a;
                pw[2] = hiTile ? d2b : d2a;
                pw[3] = hiTile ? d3b : d3a;
                short8 pb = __builtin_bit_cast(short8, pw);
                #pragma unroll
                for (int td = 0; td < 4; td++) {
                    short8 vf = *(const short8*)(Vs + (td * 16 + l16) * LK + ks * 32 + quad * 8);
                    oacc[td] = __builtin_amdgcn_mfma_f32_16x16x32_bf16(vf, pb, oacc[td], 0, 0, 0);
                }
            }
        }
    }

    // ---- epilogue: O = O^T / l, transpose through freed Ks, coalesced store ----
    __syncthreads();                       // everyone done with Ks/Vs
    bf16* T = Ks + wave * 16 * LK;         // per-wave 16-row slice [q][d]
    const float invl = 1.0f / l;
    #pragma unroll
    for (int td = 0; td < 4; td++)
        #pragma unroll
        for (int r = 0; r < 4; r++)
            T[l16 * LK + td * 16 + quad * 4 + r] = __float2bfloat16(oacc[td][r] * invl);
    // wave-local RAW on LDS: compiler inserts lgkm wait; no barrier needed (own slice)
    #pragma unroll
    for (int pass = 0; pass < 2; pass++) {
        const int rq = (lane >> 3) + pass * 8;
        const int dd = (lane & 7) * 8;
        short8 v8 = *(const short8*)(T + rq * LK + dd);
        *(short8*)(Q + bh + (size_t)(qrow + rq) * DH + dd) = v8;
    }
}

extern "C" void kernel_launch(void* const* d_in, const int* in_sizes, int n_in,
                              void* d_out, int out_size, void* d_ws, size_t ws_size,
                              hipStream_t stream)
{
    const float* x  = (const float*)d_in[0];
    const float* wq = (const float*)d_in[1];
    const float* wk = (const float*)d_in[2];
    const float* wv = (const float*)d_in[3];
    const float* wo = (const float*)d_in[4];
    float* out = (float*)d_out;

    // ws (>=24 MB): q | k | vT  bf16
    bf16* qb = (bf16*)d_ws;
    bf16* kb = qb + (size_t)OUTN;
    bf16* vb = kb + (size_t)OUTN;

    // d_out doubles as bf16 scratch until the final GEMM overwrites it
    bf16* xb  = (bf16*)d_out;
    bf16* wqb = xb + (size_t)OUTN;
    bf16* wkb = wqb + WN;
    bf16* wvb = wkb + WN;

    cvt_inputs<<<(OUTN + 3 * WN) / (8 * 256), 256, 0, stream>>>(x, wq, wk, wv, xb);
    gemm_mfma<0><<<dim3(DM / 128, MROWS / 128, 3), dim3(256), 0, stream>>>(
        xb, wqb, wkb, wvb, qb, kb, vb, nullptr);
    attn_flash<<<dim3(SEQ / 64, NH, BATCH), dim3(256), 0, stream>>>(qb, kb, vb);
    bf16* wob = kb;    // kb dead after attention
    cvt_wo<<<WN / (8 * 256), 256, 0, stream>>>(wo, wob);
    gemm_mfma<1><<<dim3(DM / 128, MROWS / 128, 1), dim3(256), 0, stream>>>(
        qb, wob, nullptr, nullptr, nullptr, nullptr, nullptr, out);
}

// Round 11
// 202.509 us; speedup vs baseline: 1.2392x; 1.0473x over previous
//
#include <hip/hip_runtime.h>
#include <hip/hip_bf16.h>
#include <stdint.h>

using bf16 = __hip_bfloat16;
typedef __attribute__((ext_vector_type(8))) short short8;
typedef __attribute__((ext_vector_type(4))) float floatx4;
typedef __attribute__((ext_vector_type(4))) unsigned int uintx4;

constexpr int BATCH = 2;
constexpr int SEQ   = 2048;
constexpr int NH    = 16;
constexpr int DH    = 64;
constexpr int DM    = 1024;
constexpr int MROWS = BATCH * SEQ;        // 4096
constexpr int OUTN  = MROWS * DM;         // 4194304
constexpr int WN    = DM * DM;            // 1048576

__device__ inline short bfbits(float x) {
    bf16 h = __float2bfloat16(x);
    return __builtin_bit_cast(short, h);
}

// async global->LDS, 16B per lane (m97 pattern)
__device__ inline void async16(bf16* lds, const bf16* g) {
    __builtin_amdgcn_global_load_lds(
        (const __attribute__((address_space(1))) unsigned int*)g,
        (__attribute__((address_space(3))) unsigned int*)lds, 16, 0, 0);
}

// ============ fp32 -> bf16 pre-convert: x|wq|wk|wv into d_out scratch ============
__global__ __launch_bounds__(256)
void cvt_inputs(const float* __restrict__ x,  const float* __restrict__ wq,
                const float* __restrict__ wk, const float* __restrict__ wv,
                bf16* __restrict__ dst)
{
    const size_t i = ((size_t)blockIdx.x * 256 + threadIdx.x) * 8;
    const float* src; size_t off;
    if (i < (size_t)OUTN)               { src = x;  off = i; }
    else if (i < (size_t)OUTN + WN)     { src = wq; off = i - OUTN; }
    else if (i < (size_t)OUTN + 2 * WN) { src = wk; off = i - OUTN - WN; }
    else                                { src = wv; off = i - OUTN - 2 * (size_t)WN; }
    float4 f0 = *(const float4*)(src + off);
    float4 f1 = *(const float4*)(src + off + 4);
    short8 o;
    o[0] = bfbits(f0.x); o[1] = bfbits(f0.y); o[2] = bfbits(f0.z); o[3] = bfbits(f0.w);
    o[4] = bfbits(f1.x); o[5] = bfbits(f1.y); o[6] = bfbits(f1.z); o[7] = bfbits(f1.w);
    *(short8*)(dst + i) = o;
}

__global__ __launch_bounds__(256)
void cvt_wo(const float* __restrict__ wo, bf16* __restrict__ dst)
{
    const size_t i = ((size_t)blockIdx.x * 256 + threadIdx.x) * 8;
    float4 f0 = *(const float4*)(wo + i);
    float4 f1 = *(const float4*)(wo + i + 4);
    short8 o;
    o[0] = bfbits(f0.x); o[1] = bfbits(f0.y); o[2] = bfbits(f0.z); o[3] = bfbits(f0.w);
    o[4] = bfbits(f1.x); o[5] = bfbits(f1.y); o[6] = bfbits(f1.z); o[7] = bfbits(f1.w);
    *(short8*)(dst + i) = o;
}

// ============ bf16 MFMA GEMM, global_load_lds staging, M-tile 128 x N-tile NT ============
// MODE 0 (NT=128): A = xb; z selects (wq->q PRESCALED 0.125*log2e)(wk->k)(wv->vT)
// MODE 1 (NT=64):  A gathered from [B,H,S,DH]; output fp32 row-major [B,S,DM]
template<int MODE, int NT>
__global__ __launch_bounds__(256)
void gemm_mfma(const bf16* __restrict__ A,
               const bf16* __restrict__ W0, const bf16* __restrict__ W1,
               const bf16* __restrict__ W2,
               bf16* __restrict__ C0, bf16* __restrict__ C1, bf16* __restrict__ C2,
               float* __restrict__ F)
{
    constexpr int NJ = NT / 32;               // j-frags per wave (4 or 2)
    __shared__ __align__(16) bf16 As[128 * 32];
    __shared__ __align__(16) bf16 Ws[NT * 32];

    const int t    = threadIdx.x;
    const int wave = t >> 6;
    const int lane = t & 63;
    const int quad = lane >> 4;
    const int l16  = lane & 15;
    const int m0 = blockIdx.y * 128;
    const int n0 = blockIdx.x * NT;
    const int wr = (wave >> 1) * 64;
    const int wc = (wave & 1) * (NT / 2);

    const int z = (MODE == 0) ? blockIdx.z : 0;
    const bf16* W = (z == 0) ? W0 : ((z == 1) ? W1 : W2);

    const int c    = t;
    bf16* lA0 = As + c * 8;          bf16* lA1 = As + c * 8 + 2048;
    bf16* lW0 = Ws + c * 8;          bf16* lW1 = Ws + c * 8 + 2048;
    const int ar0 = m0 + (c >> 2),  ar1 = m0 + 64 + (c >> 2);
    const int nr0 = n0 + (c >> 2),  nr1 = n0 + 64 + (c >> 2);
    const int kc  = (c & 3) * 8;

    floatx4 acc[4][NJ] = {};

    for (int k0 = 0; k0 < DM; k0 += 32) {
        const bf16 *gA0, *gA1;
        if (MODE == 0) {
            gA0 = A + (size_t)ar0 * DM + k0 + kc;
            gA1 = A + (size_t)ar1 * DM + k0 + kc;
        } else {
            const int k = k0 + kc, h = k >> 6, d = k & (DH - 1);
            gA0 = A + (((size_t)((ar0 >> 11) * NH + h)) * SEQ + (ar0 & (SEQ - 1))) * DH + d;
            gA1 = A + (((size_t)((ar1 >> 11) * NH + h)) * SEQ + (ar1 & (SEQ - 1))) * DH + d;
        }
        const bf16* gW0 = W + (size_t)nr0 * DM + k0 + kc;
        const bf16* gW1 = W + (size_t)nr1 * DM + k0 + kc;

        __syncthreads();
        async16(lA0, gA0);
        async16(lA1, gA1);
        async16(lW0, gW0);
        if (NT == 128) async16(lW1, gW1);
        __syncthreads();

        short8 af[4], wf[NJ];
        #pragma unroll
        for (int i = 0; i < 4; i++)
            af[i] = *(const short8*)(As + (wr + i * 16 + l16) * 32 + quad * 8);
        #pragma unroll
        for (int j = 0; j < NJ; j++)
            wf[j] = *(const short8*)(Ws + (wc + j * 16 + l16) * 32 + quad * 8);
        #pragma unroll
        for (int i = 0; i < 4; i++)
            #pragma unroll
            for (int j = 0; j < NJ; j++)
                acc[i][j] = __builtin_amdgcn_mfma_f32_16x16x32_bf16(af[i], wf[j], acc[i][j], 0, 0, 0);
    }

    // C/D layout: col = lane&15, row = quad*4 + reg  [m89/m91]
    #pragma unroll
    for (int i = 0; i < 4; i++) {
        #pragma unroll
        for (int j = 0; j < NJ; j++) {
            #pragma unroll
            for (int r = 0; r < 4; r++) {
                const int gm = m0 + wr + i * 16 + quad * 4 + r;
                const int gn = n0 + wc + j * 16 + l16;
                if (MODE == 1) {
                    F[(size_t)gm * DM + gn] = acc[i][j][r];
                } else {
                    const int b = gm >> 11, s = gm & (SEQ - 1);
                    const int h = gn >> 6,  d = gn & (DH - 1);
                    float av = acc[i][j][r];
                    if (z == 0) av *= 0.18033688f;    // (1/sqrt(DH)) * log2(e) for exp2 softmax
                    const bf16 val = __float2bfloat16(av);
                    if (z == 2)
                        C2[(((size_t)(b * NH + h)) * DH + d) * SEQ + s] = val;   // V^T
                    else if (z == 0)
                        C0[(((size_t)(b * NH + h)) * SEQ + s) * DH + d] = val;
                    else
                        C1[(((size_t)(b * NH + h)) * SEQ + s) * DH + d] = val;
                }
            }
        }
    }
}

// ============ MFMA causal flash attention (S^T form, BK=128 staging) ============
// grid (32, NH, BATCH), 4 waves, BQ=64, in-place on Q [B,H,S,DH].
// S^T = K·(cq)^T with c = 0.125*log2e folded into q; softmax in exp2 domain.
// Register-shuffle P distribution; PV as O^T = V^T·P^T.
__global__ __launch_bounds__(256)
void attn_flash(bf16* __restrict__ Q, const bf16* __restrict__ K,
                const bf16* __restrict__ Vt)
{
    constexpr int LKK = 72;    // Ks row stride: 64 dims + 8 pad
    constexpr int LKV = 136;   // Vs row stride: 128 keys + 8 pad
    __shared__ __align__(16) bf16 Ks[128 * LKK];   // [key][dim]; reused for O transpose
    __shared__ __align__(16) bf16 Vs[64 * LKV];    // [dim][key]

    const int t    = threadIdx.x;
    const int wave = t >> 6;
    const int lane = t & 63;
    const int quad = lane >> 4;
    const int l16  = lane & 15;

    const int h  = blockIdx.y;
    const int b  = blockIdx.z;
    const int qt = (blockIdx.x + 5 * h + 16 * b) & 31;   // load-balance swizzle
    const int q0 = qt * 64;
    const size_t bh = ((size_t)(b * NH + h)) * SEQ * DH;

    const int qrow = q0 + wave * 16;
    const int qg   = qrow + l16;          // this lane's q row (S^T col)

    short8 qf0 = *(const short8*)(Q + bh + (size_t)(qrow + l16) * DH + quad * 8);
    short8 qf1 = *(const short8*)(Q + bh + (size_t)(qrow + l16) * DH + quad * 8 + 32);

    floatx4 oacc[4] = {};                 // O^T tiles
    float m = -1e30f, l = 0.f;            // per-lane scalars (exp2 domain)

    const int krow = t >> 3;              // 0..31
    const int kcol = (t & 7) * 8;         // 0..56
    const int vrow = t >> 4;              // 0..15
    const int vcol = (t & 15) * 8;        // 0..120

    const int sA = (2 * (quad & 1)) * 16 + l16;
    const int sB = sA + 16;
    const bool hiTile = (quad >= 2);

    for (int k0 = 0; k0 < q0 + 64; k0 += 128) {
        uintx4 kv[4], vv[4];
        #pragma unroll
        for (int p = 0; p < 4; p++) {
            kv[p] = *(const uintx4*)(K  + bh + (size_t)(k0 + p * 32 + krow) * DH + kcol);
            vv[p] = *(const uintx4*)(Vt + bh + (size_t)(p * 16 + vrow) * SEQ + k0 + vcol);
        }
        __syncthreads();
        #pragma unroll
        for (int p = 0; p < 4; p++) {
            *(uintx4*)(Ks + (p * 32 + krow) * LKK + kcol) = kv[p];
            *(uintx4*)(Vs + (p * 16 + vrow) * LKV + vcol) = vv[p];
        }
        __syncthreads();

        #pragma unroll
        for (int c64 = 0; c64 < 128; c64 += 64) {
            const int kb0 = k0 + c64;
            if (kb0 > qrow + 15) continue;

            // ---- S^T[key][q] ----
            floatx4 sc[4];
            #pragma unroll
            for (int jj = 0; jj < 4; jj++) {
                short8 kf0 = *(const short8*)(Ks + (c64 + jj * 16 + l16) * LKK + quad * 8);
                short8 kf1 = *(const short8*)(Ks + (c64 + jj * 16 + l16) * LKK + quad * 8 + 32);
                floatx4 cc = {};
                cc = __builtin_amdgcn_mfma_f32_16x16x32_bf16(kf0, qf0, cc, 0, 0, 0);
                cc = __builtin_amdgcn_mfma_f32_16x16x32_bf16(kf1, qf1, cc, 0, 0, 0);
                sc[jj] = cc;   // key = kb0 + jj*16 + quad*4 + r ; q = qg
            }
            // ---- causal mask on the diagonal chunk ----
            if (kb0 + 63 > qrow) {
                #pragma unroll
                for (int jj = 0; jj < 4; jj++) {
                    const int kgb = kb0 + jj * 16 + quad * 4;
                    #pragma unroll
                    for (int r = 0; r < 4; r++)
                        sc[jj][r] = (kgb + r <= qg) ? sc[jj][r] : -1e30f;
                }
            }
            // ---- online softmax (exp2 domain, per-lane scalars) ----
            float mx = sc[0][0];
            #pragma unroll
            for (int jj = 0; jj < 4; jj++)
                #pragma unroll
                for (int r = 0; r < 4; r++) mx = fmaxf(mx, sc[jj][r]);
            mx = fmaxf(mx, __shfl_xor(mx, 16, 64));
            mx = fmaxf(mx, __shfl_xor(mx, 32, 64));
            const float mnew  = fmaxf(m, mx);
            const float alpha = __builtin_amdgcn_exp2f(m - mnew);
            float rs = 0.f;
            #pragma unroll
            for (int jj = 0; jj < 4; jj++)
                #pragma unroll
                for (int r = 0; r < 4; r++) {
                    const float p = __builtin_amdgcn_exp2f(sc[jj][r] - mnew);
                    sc[jj][r] = p;
                    rs += p;
                }
            rs += __shfl_xor(rs, 16, 64);
            rs += __shfl_xor(rs, 32, 64);
            l = l * alpha + rs;
            m = mnew;
            #pragma unroll
            for (int td = 0; td < 4; td++)
                #pragma unroll
                for (int r = 0; r < 4; r++) oacc[td][r] *= alpha;

            // ---- pack P rows into dwords ----
            unsigned lo[4], hi[4];
            #pragma unroll
            for (int jj = 0; jj < 4; jj++) {
                lo[jj] = (unsigned)(unsigned short)bfbits(sc[jj][0]) |
                         ((unsigned)(unsigned short)bfbits(sc[jj][1]) << 16);
                hi[jj] = (unsigned)(unsigned short)bfbits(sc[jj][2]) |
                         ((unsigned)(unsigned short)bfbits(sc[jj][3]) << 16);
            }
            // ---- shuffle-distribute P^T B-frags + PV MFMA ----
            #pragma unroll
            for (int ks = 0; ks < 2; ks++) {
                unsigned d0a = __shfl((int)lo[2 * ks],     sA, 64);
                unsigned d0b = __shfl((int)lo[2 * ks + 1], sA, 64);
                unsigned d1a = __shfl((int)hi[2 * ks],     sA, 64);
                unsigned d1b = __shfl((int)hi[2 * ks + 1], sA, 64);
                unsigned d2a = __shfl((int)lo[2 * ks],     sB, 64);
                unsigned d2b = __shfl((int)lo[2 * ks + 1], sB, 64);
                unsigned d3a = __shfl((int)hi[2 * ks],     sB, 64);
                unsigned d3b = __shfl((int)hi[2 * ks + 1], sB, 64);
                uintx4 pw;
                pw[0] = hiTile ? d0b : d0a;
                pw[1] = hiTile ? d1b : d1a;
                pw[2] = hiTile ? d2b : d2a;
                pw[3] = hiTile ? d3b : d3a;
                short8 pb = __builtin_bit_cast(short8, pw);
                #pragma unroll
                for (int td = 0; td < 4; td++) {
                    short8 vf = *(const short8*)(Vs + (td * 16 + l16) * LKV + c64 + ks * 32 + quad * 8);
                    oacc[td] = __builtin_amdgcn_mfma_f32_16x16x32_bf16(vf, pb, oacc[td], 0, 0, 0);
                }
            }
        }
    }

    // ---- epilogue: O = O^T / l, transpose through freed Ks, coalesced store ----
    __syncthreads();
    bf16* T = Ks + wave * 16 * LKK;
    const float invl = 1.0f / l;
    #pragma unroll
    for (int td = 0; td < 4; td++)
        #pragma unroll
        for (int r = 0; r < 4; r++)
            T[l16 * LKK + td * 16 + quad * 4 + r] = __float2bfloat16(oacc[td][r] * invl);
    #pragma unroll
    for (int pass = 0; pass < 2; pass++) {
        const int rq = (lane >> 3) + pass * 8;
        const int dd = (lane & 7) * 8;
        short8 v8 = *(const short8*)(T + rq * LKK + dd);
        *(short8*)(Q + bh + (size_t)(qrow + rq) * DH + dd) = v8;
    }
}

extern "C" void kernel_launch(void* const* d_in, const int* in_sizes, int n_in,
                              void* d_out, int out_size, void* d_ws, size_t ws_size,
                              hipStream_t stream)
{
    const float* x  = (const float*)d_in[0];
    const float* wq = (const float*)d_in[1];
    const float* wk = (const float*)d_in[2];
    const float* wv = (const float*)d_in[3];
    const float* wo = (const float*)d_in[4];
    float* out = (float*)d_out;

    // ws (>=24 MB): q | k | vT  bf16
    bf16* qb = (bf16*)d_ws;
    bf16* kb = qb + (size_t)OUTN;
    bf16* vb = kb + (size_t)OUTN;

    // d_out doubles as bf16 scratch until the final GEMM overwrites it
    bf16* xb  = (bf16*)d_out;
    bf16* wqb = xb + (size_t)OUTN;
    bf16* wkb = wqb + WN;
    bf16* wvb = wkb + WN;

    cvt_inputs<<<(OUTN + 3 * WN) / (8 * 256), 256, 0, stream>>>(x, wq, wk, wv, xb);
    gemm_mfma<0, 128><<<dim3(DM / 128, MROWS / 128, 3), dim3(256), 0, stream>>>(
        xb, wqb, wkb, wvb, qb, kb, vb, nullptr);
    attn_flash<<<dim3(SEQ / 64, NH, BATCH), dim3(256), 0, stream>>>(qb, kb, vb);
    bf16* wob = kb;    // kb dead after attention
    cvt_wo<<<WN / (8 * 256), 256, 0, stream>>>(wo, wob);
    gemm_mfma<1, 64><<<dim3(DM / 64, MROWS / 128, 1), dim3(256), 0, stream>>>(
        qb, wob, nullptr, nullptr, nullptr, nullptr, nullptr, out);
}